// Round 2
// baseline (317.766 us; speedup 1.0000x reference)
//
#include <hip/hip_runtime.h>

#define D_MODEL 128
#define D_INNER 256
#define D_STATE 256
#define LEN 100
#define NR 400   // B*L

__device__ __forceinline__ float siluf_(float x) { return x / (1.0f + __expf(-x)); }
__device__ __forceinline__ float softplusf_(float x) {
    return (x > 20.f) ? x : log1pf(expf(x));
}

// K1: xz = hidden @ in_proj_w.T + b   (400 x 512, K=128)
__global__ void k_inproj(const float* __restrict__ hidden, const float* __restrict__ w,
                         const float* __restrict__ b, float* __restrict__ xz) {
    int idx = blockIdx.x * 256 + threadIdx.x;     // 204800
    int r = idx >> 9, j = idx & 511;
    const float* hp = hidden + r * D_MODEL;
    const float* wp = w + j * D_MODEL;
    float acc = 0.f;
#pragma unroll
    for (int k = 0; k < D_MODEL; k += 4) {
        float4 a = *reinterpret_cast<const float4*>(hp + k);
        float4 c = *reinterpret_cast<const float4*>(wp + k);
        acc += a.x * c.x + a.y * c.y + a.z * c.z + a.w * c.w;
    }
    xz[idx] = acc + b[j];
}

// K2: negA = -exp(A_log)  (256x256 f32 table)
__global__ void k_nega(const float* __restrict__ alog, float* __restrict__ negA) {
    int i = blockIdx.x * 256 + threadIdx.x;       // 65536
    negA[i] = -expf(alog[i]);
}

// K3: causal depthwise conv (d_conv=4) + bias + silu
__global__ void k_conv(const float* __restrict__ xz, const float* __restrict__ cw,
                       const float* __restrict__ cb, float* __restrict__ xact) {
    int idx = blockIdx.x * 256 + threadIdx.x;     // 102400
    int r = idx >> 8, c = idx & 255;
    int l = r % LEN;
    float4 w = *reinterpret_cast<const float4*>(cw + c * 4);
    float acc = cb[c];
    if (l >= 3) acc += xz[(r - 3) * 512 + c] * w.x;
    if (l >= 2) acc += xz[(r - 2) * 512 + c] * w.y;
    if (l >= 1) acc += xz[(r - 1) * 512 + c] * w.z;
    acc += xz[r * 512 + c] * w.w;
    xact[idx] = siluf_(acc);
}

// K4: Bm = x @ x_proj_w[0:256].T ; dt = softplus(x @ dt_proj_w.T + b)
__global__ void k_bdt(const float* __restrict__ xact, const float* __restrict__ xw,
                      const float* __restrict__ dtw, const float* __restrict__ dtb,
                      float* __restrict__ Bm, float* __restrict__ dt) {
    int idx = blockIdx.x * 256 + threadIdx.x;     // 204800
    int r = idx >> 9, j = idx & 511;
    bool isB = (j < 256);
    int jj = isB ? j : (j - 256);
    const float* xp = xact + r * 256;
    const float* wp = (isB ? xw : dtw) + jj * 256;
    float acc = 0.f;
#pragma unroll 4
    for (int k = 0; k < 256; k += 4) {
        float4 a = *reinterpret_cast<const float4*>(xp + k);
        float4 c = *reinterpret_cast<const float4*>(wp + k);
        acc += a.x * c.x + a.y * c.y + a.z * c.z + a.w * c.w;
    }
    if (isB) Bm[r * 256 + jj] = acc;
    else     dt[r * 256 + jj] = softplusf_(acc + dtb[jj]);
}

// K5: main scan. block = (r, d-slice of 32); thread owns 4 n-columns (float4).
// as[d,n] = state[d,n]*exp(dt[d]*negA[d,n]) + dt[d]*Bm[n]; ypart[n] += as*C[l,d,n]
__global__ void k_scan(const float* __restrict__ state, const float* __restrict__ negA,
                       const float* __restrict__ Cp, const float* __restrict__ dt,
                       const float* __restrict__ Bm, float* __restrict__ ostate,
                       float* __restrict__ ypart) {
    int bid = blockIdx.x;            // 3200 = 400 rows * 8 slices
    int r = bid >> 3, sl = bid & 7, d0 = sl * 32;
    int l = r % LEN;
    int t = threadIdx.x;             // 0..63
    int n0 = t * 4;
    __shared__ float dts[32];
    if (t < 32) dts[t] = dt[r * 256 + d0 + t];
    __syncthreads();
    float4 Bv = *reinterpret_cast<const float4*>(Bm + r * 256 + n0);
    const float* sp = state + ((size_t)(r * 256 + d0)) * 256 + n0;
    const float* cp = Cp + ((size_t)(l * 256 + d0)) * 256 + n0;
    const float* ap = negA + d0 * 256 + n0;
    float* op = ostate + ((size_t)(r * 256 + d0)) * 256 + n0;
    float4 acc = make_float4(0.f, 0.f, 0.f, 0.f);
#pragma unroll 4
    for (int dd = 0; dd < 32; ++dd) {
        float dtv = dts[dd];
        float4 s = *reinterpret_cast<const float4*>(sp + (size_t)dd * 256);
        float4 c = *reinterpret_cast<const float4*>(cp + (size_t)dd * 256);
        float4 a = *reinterpret_cast<const float4*>(ap + dd * 256);
        float4 as;
        as.x = s.x * __expf(dtv * a.x) + dtv * Bv.x;
        as.y = s.y * __expf(dtv * a.y) + dtv * Bv.y;
        as.z = s.z * __expf(dtv * a.z) + dtv * Bv.z;
        as.w = s.w * __expf(dtv * a.w) + dtv * Bv.w;
        *reinterpret_cast<float4*>(op + (size_t)dd * 256) = as;
        acc.x += as.x * c.x;
        acc.y += as.y * c.y;
        acc.z += as.z * c.z;
        acc.w += as.w * c.w;
    }
    *reinterpret_cast<float4*>(ypart + ((size_t)(sl * NR + r)) * 256 + n0) = acc;
}

// K6: y = (sum_sl ypart + D1*x) * silu(z)
__global__ void k_yfin(const float* __restrict__ ypart, const float* __restrict__ xact,
                       const float* __restrict__ xz, const float* __restrict__ D1,
                       float* __restrict__ y) {
    int idx = blockIdx.x * 256 + threadIdx.x;     // 102400
    int r = idx >> 8, n = idx & 255;
    const int S = NR * 256;
    float s = 0.f;
#pragma unroll
    for (int q = 0; q < 8; q++) s += ypart[q * S + idx];
    s += D1[n] * xact[idx];
    y[idx] = s * siluf_(xz[r * 512 + 256 + n]);
}

// K7: out = y @ out_proj_w.T + b  -> f32
__global__ void k_outproj(const float* __restrict__ y, const float* __restrict__ ow,
                          const float* __restrict__ ob, float* __restrict__ out) {
    int idx = blockIdx.x * 256 + threadIdx.x;     // 51200
    int r = idx >> 7, m = idx & 127;
    const float* yp = y + r * 256;
    const float* wp = ow + m * 256;
    float acc = ob[m];
#pragma unroll 4
    for (int k = 0; k < 256; k += 4) {
        float4 a = *reinterpret_cast<const float4*>(yp + k);
        float4 c = *reinterpret_cast<const float4*>(wp + k);
        acc += a.x * c.x + a.y * c.y + a.z * c.z + a.w * c.w;
    }
    out[idx] = acc;
}

extern "C" void kernel_launch(void* const* d_in, const int* in_sizes, int n_in,
                              void* d_out, int out_size, void* d_ws, size_t ws_size,
                              hipStream_t stream) {
    const float* hidden = (const float*)d_in[0];
    const float* state  = (const float*)d_in[1];
    const float* ipw    = (const float*)d_in[2];
    const float* ipb    = (const float*)d_in[3];
    const float* cw     = (const float*)d_in[4];
    const float* cb     = (const float*)d_in[5];
    const float* xpw    = (const float*)d_in[6];
    const float* dtw    = (const float*)d_in[7];
    const float* dtb    = (const float*)d_in[8];
    const float* alog   = (const float*)d_in[9];
    const float* D1     = (const float*)d_in[10];
    const float* Cp     = (const float*)d_in[11];
    const float* opw    = (const float*)d_in[12];
    const float* opb    = (const float*)d_in[13];

    float* out    = (float*)d_out;             // (4,100,128) = 51200
    float* ostate = out + 51200;               // (4,100,256,256)

    float* ws    = (float*)d_ws;
    float* xz    = ws;                 // 204800  (x = cols 0..255, z = 256..511)
    float* xact  = ws + 204800;        // 102400
    float* Bm    = ws + 307200;        // 102400
    float* dt    = ws + 409600;        // 102400
    float* negA  = ws + 512000;        // 65536
    float* ypart = ws + 577536;        // 819200 (8 slices)
    float* y     = ws + 1396736;       // 102400

    k_inproj <<<800, 256, 0, stream>>>(hidden, ipw, ipb, xz);
    k_nega   <<<256, 256, 0, stream>>>(alog, negA);
    k_conv   <<<400, 256, 0, stream>>>(xz, cw, cb, xact);
    k_bdt    <<<800, 256, 0, stream>>>(xact, xpw, dtw, dtb, Bm, dt);
    k_scan   <<<3200, 64, 0, stream>>>(state, negA, Cp, dt, Bm, ostate, ypart);
    k_yfin   <<<400, 256, 0, stream>>>(ypart, xact, xz, D1, y);
    k_outproj<<<200, 256, 0, stream>>>(y, opw, opb, out);
}

// Round 3
// 297.336 us; speedup vs baseline: 1.0687x; 1.0687x over previous
//
#include <hip/hip_runtime.h>

#define LEN 100
#define NR 400   // B*L

__device__ __forceinline__ float siluf_(float x) { return x / (1.0f + __expf(-x)); }
__device__ __forceinline__ float softplusf_(float x) {
    return (x > 20.f) ? x : log1pf(expf(x));
}

// negA = -exp(A_log)  (256x256 f32 table)
__global__ void k_nega(const float* __restrict__ alog, float* __restrict__ negA) {
    int i = blockIdx.x * 256 + threadIdx.x;       // 65536
    negA[i] = -expf(alog[i]);
}

// Fused front: in_proj (+recompute 4 rows for conv) + causal conv + silu
//            + x_proj(B half) + dt_proj + softplus + silu(z)
// one block per row r; 256 threads, thread j owns output channel j.
__global__ void __launch_bounds__(256) k_front(
    const float* __restrict__ hidden, const float* __restrict__ ipw, const float* __restrict__ ipb,
    const float* __restrict__ cw, const float* __restrict__ cb,
    const float* __restrict__ xpw, const float* __restrict__ dtw, const float* __restrict__ dtb,
    float* __restrict__ xact, float* __restrict__ Bm, float* __restrict__ dt,
    float* __restrict__ zs)
{
    int r = blockIdx.x;          // 0..399
    int l = r % LEN;
    int j = threadIdx.x;         // 0..255
    int lb = l < 3 ? l : 3;
    __shared__ float hid[4][128];
    __shared__ __align__(16) float xs[256];

    // stage hidden rows r-k (k=0..3); zero-fill missing rows
    for (int e = j; e < 512; e += 256) {
        int k = e >> 7;
        int c = e & 127;
        hid[k][c]       = (k     <= lb) ? hidden[(size_t)(r - k)     * 128 + c] : 0.f;
        hid[k + 2][c]   = 0.f;   // overwritten below if valid
        if (k + 2 <= lb) hid[k + 2][c] = hidden[(size_t)(r - k - 2) * 128 + c];
    }
    __syncthreads();

    // x_pre for rows r-k (k=0..3) and z for row r
    float b0 = ipb[j];
    float xp0 = b0, xp1 = b0, xp2 = b0, xp3 = b0;
    float z = ipb[256 + j];
    const float* wx = ipw + (size_t)j * 128;
    const float* wz = ipw + (size_t)(256 + j) * 128;
#pragma unroll 8
    for (int c = 0; c < 128; c += 4) {
        float4 w = *(const float4*)(wx + c);
        xp0 += w.x * hid[0][c] + w.y * hid[0][c+1] + w.z * hid[0][c+2] + w.w * hid[0][c+3];
        xp1 += w.x * hid[1][c] + w.y * hid[1][c+1] + w.z * hid[1][c+2] + w.w * hid[1][c+3];
        xp2 += w.x * hid[2][c] + w.y * hid[2][c+1] + w.z * hid[2][c+2] + w.w * hid[2][c+3];
        xp3 += w.x * hid[3][c] + w.y * hid[3][c+1] + w.z * hid[3][c+2] + w.w * hid[3][c+3];
        float4 v = *(const float4*)(wz + c);
        z += v.x * hid[0][c] + v.y * hid[0][c+1] + v.z * hid[0][c+2] + v.w * hid[0][c+3];
    }
    // causal conv: out[l] = sum_k cw[3-k] * x[l-k], k=0..min(l,3)
    float4 w4 = *(const float4*)(cw + j * 4);
    float conv = cb[j] + w4.w * xp0;
    if (lb >= 1) conv += w4.z * xp1;
    if (lb >= 2) conv += w4.y * xp2;
    if (lb >= 3) conv += w4.x * xp3;
    float xa = siluf_(conv);
    xs[j] = xa;
    xact[r * 256 + j] = xa;
    zs[r * 256 + j] = siluf_(z);
    __syncthreads();

    // Bm = xact . xpw[j], dt = softplus(xact . dtw[j] + dtb[j])
    float accB = 0.f, accD = dtb[j];
    const float* bw = xpw + (size_t)j * 256;
    const float* dw = dtw + (size_t)j * 256;
#pragma unroll 8
    for (int c = 0; c < 256; c += 4) {
        float4 bwv = *(const float4*)(bw + c);
        float4 dwv = *(const float4*)(dw + c);
        float4 xv  = *(const float4*)(xs + c);
        accB += bwv.x * xv.x + bwv.y * xv.y + bwv.z * xv.z + bwv.w * xv.w;
        accD += dwv.x * xv.x + dwv.y * xv.y + dwv.z * xv.z + dwv.w * xv.w;
    }
    Bm[r * 256 + j] = accB;
    dt[r * 256 + j] = softplusf_(accD);
}

// Main scan: block = (r, 64-wide d-chunk); 4 waves, each wave a 16-row d-span.
// as[d,n] = state*exp(dt[d]*negA[d,n]) + dt[d]*Bm[n]; y[n] += as*C[l,d,n]
__global__ void __launch_bounds__(256) k_scan(
    const float* __restrict__ state, const float* __restrict__ negA,
    const float* __restrict__ Cp, const float* __restrict__ dt,
    const float* __restrict__ Bm, float* __restrict__ ostate, float* __restrict__ ypart)
{
    int bid = blockIdx.x;            // 1600 = 400 r * 4 chunks
    int r = bid >> 2, ch = bid & 3;
    int l = r % LEN;
    int tid = threadIdx.x;
    int wid = tid >> 6, lane = tid & 63, n0 = lane * 4;
    int d0 = ch * 64 + wid * 16;
    __shared__ float dts[64];
    __shared__ __align__(16) float accs[4][256];
    if (tid < 64) dts[tid] = dt[r * 256 + ch * 64 + tid];
    __syncthreads();
    float4 Bv = *(const float4*)(Bm + r * 256 + n0);
    const float* sp = state + ((size_t)(r * 256 + d0)) * 256 + n0;
    const float* cp = Cp + ((size_t)(l * 256 + d0)) * 256 + n0;
    const float* ap = negA + (size_t)d0 * 256 + n0;
    float* op = ostate + ((size_t)(r * 256 + d0)) * 256 + n0;
    float4 acc = make_float4(0.f, 0.f, 0.f, 0.f);
#pragma unroll 4
    for (int i = 0; i < 16; ++i) {
        float dtv = dts[wid * 16 + i];
        float4 s = *(const float4*)(sp + (size_t)i * 256);
        float4 c = *(const float4*)(cp + (size_t)i * 256);
        float4 a = *(const float4*)(ap + (size_t)i * 256);
        float4 as;
        as.x = s.x * __expf(dtv * a.x) + dtv * Bv.x;
        as.y = s.y * __expf(dtv * a.y) + dtv * Bv.y;
        as.z = s.z * __expf(dtv * a.z) + dtv * Bv.z;
        as.w = s.w * __expf(dtv * a.w) + dtv * Bv.w;
        *(float4*)(op + (size_t)i * 256) = as;
        acc.x += as.x * c.x;
        acc.y += as.y * c.y;
        acc.z += as.z * c.z;
        acc.w += as.w * c.w;
    }
    *(float4*)(&accs[wid][n0]) = acc;
    __syncthreads();
    if (wid == 0) {
        float4 t0 = *(const float4*)(&accs[0][n0]);
        float4 t1 = *(const float4*)(&accs[1][n0]);
        float4 t2 = *(const float4*)(&accs[2][n0]);
        float4 t3 = *(const float4*)(&accs[3][n0]);
        float4 o;
        o.x = t0.x + t1.x + t2.x + t3.x;
        o.y = t0.y + t1.y + t2.y + t3.y;
        o.z = t0.z + t1.z + t2.z + t3.z;
        o.w = t0.w + t1.w + t2.w + t3.w;
        *(float4*)(ypart + ((size_t)(ch * NR + r)) * 256 + n0) = o;
    }
}

// Fused back: y = (sum_ch ypart + D1*xact) * silu(z); out = y @ out_proj_w.T + b
__global__ void __launch_bounds__(256) k_back(
    const float* __restrict__ ypart, const float* __restrict__ xact,
    const float* __restrict__ zs, const float* __restrict__ D1,
    const float* __restrict__ ow, const float* __restrict__ ob,
    float* __restrict__ out)
{
    int r = blockIdx.x;        // 0..399
    int t = threadIdx.x;       // 0..255
    __shared__ __align__(16) float ys[256];
    const int S = NR * 256;
    int idx = r * 256 + t;
    float v = ypart[idx] + ypart[S + idx] + ypart[2 * S + idx] + ypart[3 * S + idx];
    v += D1[t] * xact[idx];
    v *= zs[idx];
    ys[t] = v;
    __syncthreads();
    if (t < 128) {
        const float* wp = ow + (size_t)t * 256;
        float acc = ob[t];
#pragma unroll 8
        for (int c = 0; c < 256; c += 4) {
            float4 w = *(const float4*)(wp + c);
            float4 x = *(const float4*)(ys + c);
            acc += w.x * x.x + w.y * x.y + w.z * x.z + w.w * x.w;
        }
        out[r * 128 + t] = acc;
    }
}

extern "C" void kernel_launch(void* const* d_in, const int* in_sizes, int n_in,
                              void* d_out, int out_size, void* d_ws, size_t ws_size,
                              hipStream_t stream) {
    const float* hidden = (const float*)d_in[0];
    const float* state  = (const float*)d_in[1];
    const float* ipw    = (const float*)d_in[2];
    const float* ipb    = (const float*)d_in[3];
    const float* cw     = (const float*)d_in[4];
    const float* cb     = (const float*)d_in[5];
    const float* xpw    = (const float*)d_in[6];
    const float* dtw    = (const float*)d_in[7];
    const float* dtb    = (const float*)d_in[8];
    const float* alog   = (const float*)d_in[9];
    const float* D1     = (const float*)d_in[10];
    const float* Cp     = (const float*)d_in[11];
    const float* opw    = (const float*)d_in[12];
    const float* opb    = (const float*)d_in[13];

    float* out    = (float*)d_out;             // (4,100,128) = 51200
    float* ostate = out + 51200;               // (4,100,256,256)

    float* ws    = (float*)d_ws;
    float* negA  = ws;                 // 65536
    float* xact  = ws + 65536;         // 102400
    float* Bm    = ws + 167936;        // 102400
    float* dt    = ws + 270336;        // 102400
    float* zs    = ws + 372736;        // 102400
    float* ypart = ws + 475136;        // 409600 (4 chunk slices)

    k_nega <<<256,  256, 0, stream>>>(alog, negA);
    k_front<<<400,  256, 0, stream>>>(hidden, ipw, ipb, cw, cb, xpw, dtw, dtb,
                                      xact, Bm, dt, zs);
    k_scan <<<1600, 256, 0, stream>>>(state, negA, Cp, dt, Bm, ostate, ypart);
    k_back <<<400,  256, 0, stream>>>(ypart, xact, zs, D1, opw, opb, out);
}

// Round 4
// 287.789 us; speedup vs baseline: 1.1042x; 1.0332x over previous
//
#include <hip/hip_runtime.h>

#define LEN 100
#define NR 400   // B*L

__device__ __forceinline__ float siluf_(float x) { return x / (1.0f + __expf(-x)); }
__device__ __forceinline__ float softplusf_(float x) {
    return (x > 20.f) ? x : log1pf(expf(x));
}

typedef float f4v __attribute__((ext_vector_type(4)));
__device__ __forceinline__ float4 nt_load4(const float* p) {
    f4v t = __builtin_nontemporal_load((const f4v*)p);
    return make_float4(t.x, t.y, t.z, t.w);
}
__device__ __forceinline__ void nt_store4(float* p, float4 v) {
    f4v t; t.x = v.x; t.y = v.y; t.z = v.z; t.w = v.w;
    __builtin_nontemporal_store(t, (f4v*)p);
}

// negA = -exp(A_log)  (256x256 f32 table)
__global__ void k_nega(const float* __restrict__ alog, float* __restrict__ negA) {
    int i = blockIdx.x * 256 + threadIdx.x;       // 65536
    negA[i] = -expf(alog[i]);
}

// Fused front: in_proj (+recompute 4 rows for conv) + causal conv + silu
//            + x_proj(B half) + dt_proj + softplus + silu(z)
__global__ void __launch_bounds__(256) k_front(
    const float* __restrict__ hidden, const float* __restrict__ ipw, const float* __restrict__ ipb,
    const float* __restrict__ cw, const float* __restrict__ cb,
    const float* __restrict__ xpw, const float* __restrict__ dtw, const float* __restrict__ dtb,
    float* __restrict__ xact, float* __restrict__ Bm, float* __restrict__ dt,
    float* __restrict__ zs)
{
    int r = blockIdx.x;          // 0..399
    int l = r % LEN;
    int j = threadIdx.x;         // 0..255
    int lb = l < 3 ? l : 3;
    __shared__ float hid[4][128];
    __shared__ __align__(16) float xs[256];

    // stage hidden rows r-k (k=0..3); zero-fill rows before sequence start
    for (int e = j; e < 512; e += 256) {
        int k = e >> 7;
        int c = e & 127;
        hid[k][c] = (k <= lb) ? hidden[(size_t)(r - k) * 128 + c] : 0.f;
    }
    __syncthreads();

    // x_pre for rows r-k (k=0..3) and z for row r
    float b0 = ipb[j];
    float xp0 = b0, xp1 = b0, xp2 = b0, xp3 = b0;
    float z = ipb[256 + j];
    const float* wx = ipw + (size_t)j * 128;
    const float* wz = ipw + (size_t)(256 + j) * 128;
#pragma unroll 8
    for (int c = 0; c < 128; c += 4) {
        float4 w = *(const float4*)(wx + c);
        xp0 += w.x * hid[0][c] + w.y * hid[0][c+1] + w.z * hid[0][c+2] + w.w * hid[0][c+3];
        xp1 += w.x * hid[1][c] + w.y * hid[1][c+1] + w.z * hid[1][c+2] + w.w * hid[1][c+3];
        xp2 += w.x * hid[2][c] + w.y * hid[2][c+1] + w.z * hid[2][c+2] + w.w * hid[2][c+3];
        xp3 += w.x * hid[3][c] + w.y * hid[3][c+1] + w.z * hid[3][c+2] + w.w * hid[3][c+3];
        float4 v = *(const float4*)(wz + c);
        z += v.x * hid[0][c] + v.y * hid[0][c+1] + v.z * hid[0][c+2] + v.w * hid[0][c+3];
    }
    // causal conv: out[l] = sum_k cw[3-k] * x[l-k]
    float4 w4 = *(const float4*)(cw + j * 4);
    float conv = cb[j] + w4.w * xp0;
    if (lb >= 1) conv += w4.z * xp1;
    if (lb >= 2) conv += w4.y * xp2;
    if (lb >= 3) conv += w4.x * xp3;
    float xa = siluf_(conv);
    xs[j] = xa;
    xact[r * 256 + j] = xa;
    zs[r * 256 + j] = siluf_(z);
    __syncthreads();

    // Bm = xs . xpw[j], dt = softplus(xs . dtw[j] + dtb[j])
    float accB = 0.f, accD = dtb[j];
    const float* bw = xpw + (size_t)j * 256;
    const float* dw = dtw + (size_t)j * 256;
#pragma unroll 8
    for (int c = 0; c < 256; c += 4) {
        float4 bwv = *(const float4*)(bw + c);
        float4 dwv = *(const float4*)(dw + c);
        float4 xv  = *(const float4*)(xs + c);
        accB += bwv.x * xv.x + bwv.y * xv.y + bwv.z * xv.z + bwv.w * xv.w;
        accD += dwv.x * xv.x + dwv.y * xv.y + dwv.z * xv.z + dwv.w * xv.w;
    }
    Bm[r * 256 + j] = accB;
    dt[r * 256 + j] = softplusf_(accD);
}

// Main scan: block = (r, 32-wide d-slice); 4 waves, each wave 8 d-rows,
// explicit 1-deep register prefetch to keep loads in flight.
__global__ void __launch_bounds__(256, 8) k_scan(
    const float* __restrict__ state, const float* __restrict__ negA,
    const float* __restrict__ Cp, const float* __restrict__ dt,
    const float* __restrict__ Bm, float* __restrict__ ostate, float* __restrict__ ypart)
{
    int bid = blockIdx.x;            // 3200 = 400 r * 8 slices
    int r = bid >> 3, sl = bid & 7;
    int l = r % LEN;
    int tid = threadIdx.x;
    int wid = tid >> 6, lane = tid & 63, n0 = lane * 4;
    int d0 = sl * 32 + wid * 8;
    const float* dtp = dt + r * 256 + d0;           // wave-uniform
    float4 Bv = *(const float4*)(Bm + r * 256 + n0);
    const float* sp = state + ((size_t)(r * 256 + d0)) * 256 + n0;
    const float* cp = Cp + ((size_t)(l * 256 + d0)) * 256 + n0;
    const float* ap = negA + (size_t)d0 * 256 + n0;
    float* op = ostate + ((size_t)(r * 256 + d0)) * 256 + n0;

    __shared__ __align__(16) float accs[4][256];

    float4 acc = make_float4(0.f, 0.f, 0.f, 0.f);
    float4 s = nt_load4(sp);
    float4 c = *(const float4*)(cp);
    float4 a = *(const float4*)(ap);
#pragma unroll
    for (int i = 0; i < 8; ++i) {
        float4 s1, c1, a1;
        if (i < 7) {
            s1 = nt_load4(sp + (size_t)(i + 1) * 256);
            c1 = *(const float4*)(cp + (size_t)(i + 1) * 256);
            a1 = *(const float4*)(ap + (size_t)(i + 1) * 256);
        }
        float dtv = dtp[i];
        float4 as;
        as.x = s.x * __expf(dtv * a.x) + dtv * Bv.x;
        as.y = s.y * __expf(dtv * a.y) + dtv * Bv.y;
        as.z = s.z * __expf(dtv * a.z) + dtv * Bv.z;
        as.w = s.w * __expf(dtv * a.w) + dtv * Bv.w;
        nt_store4(op + (size_t)i * 256, as);
        acc.x += as.x * c.x;
        acc.y += as.y * c.y;
        acc.z += as.z * c.z;
        acc.w += as.w * c.w;
        if (i < 7) { s = s1; c = c1; a = a1; }
    }
    *(float4*)(&accs[wid][n0]) = acc;
    __syncthreads();
    if (wid == 0) {
        float4 t0 = *(const float4*)(&accs[0][n0]);
        float4 t1 = *(const float4*)(&accs[1][n0]);
        float4 t2 = *(const float4*)(&accs[2][n0]);
        float4 t3 = *(const float4*)(&accs[3][n0]);
        float4 o;
        o.x = t0.x + t1.x + t2.x + t3.x;
        o.y = t0.y + t1.y + t2.y + t3.y;
        o.z = t0.z + t1.z + t2.z + t3.z;
        o.w = t0.w + t1.w + t2.w + t3.w;
        *(float4*)(ypart + ((size_t)(sl * NR + r)) * 256 + n0) = o;
    }
}

// Fused back: y = (sum_sl ypart + D1*xact) * silu(z); out = y @ out_proj_w.T + b
__global__ void __launch_bounds__(256) k_back(
    const float* __restrict__ ypart, const float* __restrict__ xact,
    const float* __restrict__ zs, const float* __restrict__ D1,
    const float* __restrict__ ow, const float* __restrict__ ob,
    float* __restrict__ out)
{
    int r = blockIdx.x;        // 0..399
    int t = threadIdx.x;       // 0..255
    __shared__ __align__(16) float ys[256];
    const int S = NR * 256;
    int idx = r * 256 + t;
    float v = 0.f;
#pragma unroll
    for (int q = 0; q < 8; q++) v += ypart[q * S + idx];
    v += D1[t] * xact[idx];
    v *= zs[idx];
    ys[t] = v;
    __syncthreads();
    if (t < 128) {
        const float* wp = ow + (size_t)t * 256;
        float acc = ob[t];
#pragma unroll 8
        for (int c = 0; c < 256; c += 4) {
            float4 w = *(const float4*)(wp + c);
            float4 x = *(const float4*)(ys + c);
            acc += w.x * x.x + w.y * x.y + w.z * x.z + w.w * x.w;
        }
        out[r * 128 + t] = acc;
    }
}

extern "C" void kernel_launch(void* const* d_in, const int* in_sizes, int n_in,
                              void* d_out, int out_size, void* d_ws, size_t ws_size,
                              hipStream_t stream) {
    const float* hidden = (const float*)d_in[0];
    const float* state  = (const float*)d_in[1];
    const float* ipw    = (const float*)d_in[2];
    const float* ipb    = (const float*)d_in[3];
    const float* cw     = (const float*)d_in[4];
    const float* cb     = (const float*)d_in[5];
    const float* xpw    = (const float*)d_in[6];
    const float* dtw    = (const float*)d_in[7];
    const float* dtb    = (const float*)d_in[8];
    const float* alog   = (const float*)d_in[9];
    const float* D1     = (const float*)d_in[10];
    const float* Cp     = (const float*)d_in[11];
    const float* opw    = (const float*)d_in[12];
    const float* opb    = (const float*)d_in[13];

    float* out    = (float*)d_out;             // (4,100,128) = 51200
    float* ostate = out + 51200;               // (4,100,256,256)

    float* ws    = (float*)d_ws;
    float* negA  = ws;                 // 65536
    float* xact  = ws + 65536;         // 102400
    float* Bm    = ws + 167936;        // 102400
    float* dt    = ws + 270336;        // 102400
    float* zs    = ws + 372736;        // 102400
    float* ypart = ws + 475136;        // 819200 (8 slices)

    k_nega <<<256,  256, 0, stream>>>(alog, negA);
    k_front<<<400,  256, 0, stream>>>(hidden, ipw, ipb, cw, cb, xpw, dtw, dtb,
                                      xact, Bm, dt, zs);
    k_scan <<<3200, 256, 0, stream>>>(state, negA, Cp, dt, Bm, ostate, ypart);
    k_back <<<400,  256, 0, stream>>>(ypart, xact, zs, D1, opw, opb, out);
}